// Round 18
// baseline (686.626 us; speedup 1.0000x reference)
//
#include <hip/hip_runtime.h>
#include <hip/hip_bf16.h>

#define DH 128          // feature dim (D_IN == H == 128)
#define SCB 1024        // scan elements per block
#define NCHUNK 256      // edge chunks for XCD-partitioned CSR build
#define LROW 136        // LDS row stride in shorts (256B + 16B pad)

typedef __attribute__((ext_vector_type(8))) short short8_t;
typedef __attribute__((ext_vector_type(4))) float f32x4;
typedef __attribute__((ext_vector_type(2))) float f32x2;

static __device__ __forceinline__ short f2bf(float f) {
    union { float f; unsigned u; } v; v.f = f;
    unsigned r = v.u + 0x7fffu + ((v.u >> 16) & 1u);   // RNE
    return (short)(r >> 16);
}

static __device__ __forceinline__ float bf2f(unsigned short b) {
    union { unsigned u; float f; } v; v.u = ((unsigned)b) << 16;
    return v.f;
}

static __device__ __forceinline__ short8_t cvt8(const float* p) {
    float4 a0 = *(const float4*)p;
    float4 a1 = *(const float4*)(p + 4);
    short8_t t;
    t[0] = f2bf(a0.x); t[1] = f2bf(a0.y); t[2] = f2bf(a0.z); t[3] = f2bf(a0.w);
    t[4] = f2bf(a1.x); t[5] = f2bf(a1.y); t[6] = f2bf(a1.z); t[7] = f2bf(a1.w);
    return t;
}

static __device__ __forceinline__ short8_t cvt8v(float4 a0, float4 a1) {
    short8_t t;
    t[0] = f2bf(a0.x); t[1] = f2bf(a0.y); t[2] = f2bf(a0.z); t[3] = f2bf(a0.w);
    t[4] = f2bf(a1.x); t[5] = f2bf(a1.y); t[6] = f2bf(a1.z); t[7] = f2bf(a1.w);
    return t;
}

static __device__ __forceinline__ float sigm(float x) {
    return __builtin_amdgcn_rcpf(1.f + __expf(-x));
}
static __device__ __forceinline__ float tanh_f(float x) {
    return 1.f - 2.f * __builtin_amdgcn_rcpf(__expf(2.f * x) + 1.f);
}

// ---------------- degree histogram, XCD-partitioned ----------------
__global__ __launch_bounds__(256) void deg2_k(const int* __restrict__ ei, int E,
                                              unsigned* __restrict__ cnt, int span, int chunkE) {
    int r = blockIdx.x & 7;
    int c = blockIdx.x >> 3;
    int lo = r * span, hi = lo + span;
    long long e0 = (long long)c * chunkE;
    long long e1 = e0 + chunkE; if (e1 > E) e1 = E;
    for (long long e = e0 + threadIdx.x; e < e1; e += 256) {
        int d = ei[E + e];
        if (d >= lo && d < hi) atomicAdd(&cnt[d], 1u);
    }
}

// ---------------- 3-phase grid-parallel exclusive scan ----------------
__global__ __launch_bounds__(256) void scan1_k(const unsigned* __restrict__ cnt, int N,
                                               int* __restrict__ offs, unsigned* __restrict__ bsum) {
    __shared__ unsigned s[256];
    int t = threadIdx.x;
    int i0 = blockIdx.x * SCB + t * 4;
    unsigned v0 = (i0 + 0 < N) ? cnt[i0 + 0] : 0u;
    unsigned v1 = (i0 + 1 < N) ? cnt[i0 + 1] : 0u;
    unsigned v2 = (i0 + 2 < N) ? cnt[i0 + 2] : 0u;
    unsigned v3 = (i0 + 3 < N) ? cnt[i0 + 3] : 0u;
    unsigned ts = v0 + v1 + v2 + v3;
    s[t] = ts;
    __syncthreads();
    for (int off = 1; off < 256; off <<= 1) {
        unsigned u = (t >= off) ? s[t - off] : 0u;
        __syncthreads();
        s[t] += u;
        __syncthreads();
    }
    unsigned ex = s[t] - ts;
    if (i0 + 0 < N) offs[i0 + 0] = (int)ex;
    if (i0 + 1 < N) offs[i0 + 1] = (int)(ex + v0);
    if (i0 + 2 < N) offs[i0 + 2] = (int)(ex + v0 + v1);
    if (i0 + 3 < N) offs[i0 + 3] = (int)(ex + v0 + v1 + v2);
    if (t == 255) bsum[blockIdx.x] = s[255];
}

__global__ __launch_bounds__(1024) void scan2_k(unsigned* __restrict__ bsum, int B) {
    __shared__ unsigned s[1024];
    int t = threadIdx.x;
    unsigned v = (t < B) ? bsum[t] : 0u;
    s[t] = v;
    __syncthreads();
    for (int off = 1; off < 1024; off <<= 1) {
        unsigned u = (t >= off) ? s[t - off] : 0u;
        __syncthreads();
        s[t] += u;
        __syncthreads();
    }
    if (t < B) bsum[t] = s[t] - v;
    if (t == 0) bsum[B] = s[1023];
}

__global__ void scan3_k(int* __restrict__ offs, int* __restrict__ cur,
                        float* __restrict__ dinv, const unsigned* __restrict__ cnt,
                        const unsigned* __restrict__ bsum, int N, int B) {
    int i = blockIdx.x * 256 + threadIdx.x;
    if (i < N) {
        int v = offs[i] + (int)bsum[i >> 10];
        offs[i] = v;
        cur[i] = v;
        dinv[i] = rsqrtf((float)cnt[i] + 1.0f);
    }
    if (i == 0) offs[N] = (int)bsum[B];
}

// ---------------- CSR fill, XCD-partitioned ----------------
__global__ __launch_bounds__(256) void fill2_k(const int* __restrict__ ei, int E,
                                               int* __restrict__ cur, int* __restrict__ csr_src,
                                               int span, int chunkE) {
    int r = blockIdx.x & 7;
    int c = blockIdx.x >> 3;
    int lo = r * span, hi = lo + span;
    long long e0 = (long long)c * chunkE;
    long long e1 = e0 + chunkE; if (e1 > E) e1 = E;
    for (long long e = e0 + threadIdx.x; e < e1; e += 256) {
        int d = ei[E + e];
        if (d >= lo && d < hi) {
            int pos = atomicAdd(&cur[d], 1);
            csr_src[pos] = ei[e];
        }
    }
}

// ---------------- weight prep ----------------
__global__ void f2bf6_k(const float* __restrict__ s0, const float* __restrict__ s1,
                        const float* __restrict__ s2, const float* __restrict__ s3,
                        const float* __restrict__ s4, const float* __restrict__ s5,
                        short* __restrict__ dst, int WN) {
    int i = blockIdx.x * 256 + threadIdx.x;
    if (i >= 6 * WN) return;
    int b = i / WN, r = i - b * WN;
    const float* srcs[6] = {s0, s1, s2, s3, s4, s5};
    dst[i] = f2bf(srcs[b][r]);
}

__global__ void transpose_bf2_k(const float* __restrict__ sa, const float* __restrict__ sb,
                                short* __restrict__ da, short* __restrict__ db) {
    int i = blockIdx.x * 256 + threadIdx.x;   // 2*16384
    int m = i >> 14;
    int j = i & 16383;
    int c = j >> 7, k = j & 127;
    const float* s = m ? sb : sa;
    short* d = m ? db : da;
    d[j] = f2bf(s[k * DH + c]);
}

// h1 fp32 -> packed bf16x2 table
__global__ void h1bf_k(const float* __restrict__ src, unsigned* __restrict__ dst, long long n2) {
    long long i = (long long)blockIdx.x * 256 + threadIdx.x;   // one u32 (2 floats) per thread
    if (i < n2) {
        float2 v = ((const float2*)src)[i];
        dst[i] = (unsigned)(unsigned short)f2bf(v.x) | ((unsigned)(unsigned short)f2bf(v.y) << 16);
    }
}

// ================= MFMA GEMM (fp32 A) -> pre-scaled fp8 table (HW cvt) ===========
__global__ __launch_bounds__(256, 4) void gemm_mfma_k(const float* __restrict__ A,
                                                      const short* __restrict__ Wt,
                                                      const float* __restrict__ dinv,
                                                      unsigned char* __restrict__ C, int N) {
    int tid = threadIdx.x;
    int wave = tid >> 6, lane = tid & 63;
    int lr = lane & 15, kg = lane >> 4;

    int row0 = blockIdx.x * 128 + wave * 32;
    int ar0 = min(row0 + lr, N - 1);
    int ar1 = min(row0 + 16 + lr, N - 1);
    const float* a0p = A + (size_t)ar0 * DH;
    const float* a1p = A + (size_t)ar1 * DH;
    short8_t af[2][4];
#pragma unroll
    for (int ks = 0; ks < 4; ks++) {
        af[0][ks] = cvt8(a0p + ks * 32 + kg * 8);
        af[1][ks] = cvt8(a1p + ks * 32 + kg * 8);
    }

    float di0[4], di1[4];
#pragma unroll
    for (int j = 0; j < 4; j++) {
        di0[j] = dinv[min(row0 + kg * 4 + j, N - 1)];
        di1[j] = dinv[min(row0 + 16 + kg * 4 + j, N - 1)];
    }

    short8_t bt[3][4];
#define GLOADW(slot, t) { \
    const short* wp = Wt + (size_t)((t) * 16 + lr) * DH + kg * 8; \
    bt[slot][0] = *(const short8_t*)(wp); \
    bt[slot][1] = *(const short8_t*)(wp + 32); \
    bt[slot][2] = *(const short8_t*)(wp + 64); \
    bt[slot][3] = *(const short8_t*)(wp + 96); }

    GLOADW(0, 0)
    GLOADW(1, 1)
#pragma unroll
    for (int t = 0; t < 8; t++) {
        if (t < 6) GLOADW((t + 2) % 3, t + 2)
        f32x4 acc0 = {0.f, 0.f, 0.f, 0.f};
        f32x4 acc1 = {0.f, 0.f, 0.f, 0.f};
#pragma unroll
        for (int ks = 0; ks < 4; ks++) {
            acc0 = __builtin_amdgcn_mfma_f32_16x16x32_bf16(af[0][ks], bt[t % 3][ks], acc0, 0, 0, 0);
            acc1 = __builtin_amdgcn_mfma_f32_16x16x32_bf16(af[1][ks], bt[t % 3][ks], acc1, 0, 0, 0);
        }
        int col = t * 16 + lr;
#pragma unroll
        for (int j = 0; j < 4; j++) {
            int g0 = row0 + kg * 4 + j;
            int g1 = row0 + 16 + kg * 4 + j;
            float v0 = acc0[j] * di0[j];
            float v1 = acc1[j] * di1[j];
            if (g0 < N) C[(size_t)g0 * DH + col] =
                (unsigned char)__builtin_amdgcn_cvt_pk_fp8_f32(v0, v0, 0u, false);
            if (g1 < N) C[(size_t)g1 * DH + col] =
                (unsigned char)__builtin_amdgcn_cvt_pk_fp8_f32(v1, v1, 0u, false);
        }
    }
#undef GLOADW
}

// ================= MFMA GEMM (bf16 A) -> pre-scaled fp8 table ===========
__global__ __launch_bounds__(256, 4) void gemm_mfma_bf_k(const short* __restrict__ A, // bf16 rows
                                                         const short* __restrict__ Wt,
                                                         const float* __restrict__ dinv,
                                                         unsigned char* __restrict__ C, int N) {
    int tid = threadIdx.x;
    int wave = tid >> 6, lane = tid & 63;
    int lr = lane & 15, kg = lane >> 4;

    int row0 = blockIdx.x * 128 + wave * 32;
    int ar0 = min(row0 + lr, N - 1);
    int ar1 = min(row0 + 16 + lr, N - 1);
    const short* a0p = A + (size_t)ar0 * DH;
    const short* a1p = A + (size_t)ar1 * DH;
    short8_t af[2][4];
#pragma unroll
    for (int ks = 0; ks < 4; ks++) {
        af[0][ks] = *(const short8_t*)(a0p + ks * 32 + kg * 8);
        af[1][ks] = *(const short8_t*)(a1p + ks * 32 + kg * 8);
    }

    float di0[4], di1[4];
#pragma unroll
    for (int j = 0; j < 4; j++) {
        di0[j] = dinv[min(row0 + kg * 4 + j, N - 1)];
        di1[j] = dinv[min(row0 + 16 + kg * 4 + j, N - 1)];
    }

    short8_t bt[3][4];
#define GLOADW(slot, t) { \
    const short* wp = Wt + (size_t)((t) * 16 + lr) * DH + kg * 8; \
    bt[slot][0] = *(const short8_t*)(wp); \
    bt[slot][1] = *(const short8_t*)(wp + 32); \
    bt[slot][2] = *(const short8_t*)(wp + 64); \
    bt[slot][3] = *(const short8_t*)(wp + 96); }

    GLOADW(0, 0)
    GLOADW(1, 1)
#pragma unroll
    for (int t = 0; t < 8; t++) {
        if (t < 6) GLOADW((t + 2) % 3, t + 2)
        f32x4 acc0 = {0.f, 0.f, 0.f, 0.f};
        f32x4 acc1 = {0.f, 0.f, 0.f, 0.f};
#pragma unroll
        for (int ks = 0; ks < 4; ks++) {
            acc0 = __builtin_amdgcn_mfma_f32_16x16x32_bf16(af[0][ks], bt[t % 3][ks], acc0, 0, 0, 0);
            acc1 = __builtin_amdgcn_mfma_f32_16x16x32_bf16(af[1][ks], bt[t % 3][ks], acc1, 0, 0, 0);
        }
        int col = t * 16 + lr;
#pragma unroll
        for (int j = 0; j < 4; j++) {
            int g0 = row0 + kg * 4 + j;
            int g1 = row0 + 16 + kg * 4 + j;
            float v0 = acc0[j] * di0[j];
            float v1 = acc1[j] * di1[j];
            if (g0 < N) C[(size_t)g0 * DH + col] =
                (unsigned char)__builtin_amdgcn_cvt_pk_fp8_f32(v0, v0, 0u, false);
            if (g1 < N) C[(size_t)g1 * DH + col] =
                (unsigned char)__builtin_amdgcn_cvt_pk_fp8_f32(v1, v1, 0u, false);
        }
    }
#undef GLOADW
}

// ---------------- gather: fp8 table in, packed bf16 out ----------
// dest[d] = bf16( relu( dd * ( sum_e xq[src_e] + xq[d] ) + b ) )
__global__ __launch_bounds__(256) void gather_k(const int* __restrict__ csr_src,
                                                const int* __restrict__ offs,
                                                const float* __restrict__ dinv,
                                                const unsigned short* __restrict__ xq2, // 2 fp8/ushort
                                                const float* __restrict__ bias,
                                                unsigned* __restrict__ dest, int N) {
    int wid = blockIdx.x * 4 + (threadIdx.x >> 6);
    if (wid >= N) return;
    int lane = threadIdx.x & 63;
    int j = offs[wid];
    int end = offs[wid + 1];
    float dd = dinv[wid];

    f32x2 f0 = __builtin_amdgcn_cvt_pk_f32_fp8((unsigned)xq2[(size_t)wid * 64 + lane], false);
    float ax = f0[0];
    float ay = f0[1];

#define ACC(w) { f32x2 f_ = __builtin_amdgcn_cvt_pk_f32_fp8((unsigned)(w), false); \
                 ax += f_[0]; ay += f_[1]; }

    if (j + 4 <= end) {
        int a0 = csr_src[j], a1 = csr_src[j + 1], a2 = csr_src[j + 2], a3 = csr_src[j + 3];
        j += 4;
        for (; j + 4 <= end; j += 4) {
            unsigned w0 = xq2[(size_t)a0 * 64 + lane];
            unsigned w1 = xq2[(size_t)a1 * 64 + lane];
            unsigned w2 = xq2[(size_t)a2 * 64 + lane];
            unsigned w3 = xq2[(size_t)a3 * 64 + lane];
            a0 = csr_src[j]; a1 = csr_src[j + 1]; a2 = csr_src[j + 2]; a3 = csr_src[j + 3];
            ACC(w0) ACC(w1) ACC(w2) ACC(w3)
        }
        unsigned w0 = xq2[(size_t)a0 * 64 + lane];
        unsigned w1 = xq2[(size_t)a1 * 64 + lane];
        unsigned w2 = xq2[(size_t)a2 * 64 + lane];
        unsigned w3 = xq2[(size_t)a3 * 64 + lane];
        ACC(w0) ACC(w1) ACC(w2) ACC(w3)
    }
    for (; j < end; ++j) {
        unsigned w = xq2[(size_t)csr_src[j] * 64 + lane];
        ACC(w)
    }
#undef ACC

    float2 b2 = ((const float2*)bias)[lane];
    float ox = fmaxf(fmaf(dd, ax, b2.x), 0.f);
    float oy = fmaxf(fmaf(dd, ay, b2.y), 0.f);
    unsigned o = (unsigned)(unsigned short)f2bf(ox) | ((unsigned)(unsigned short)f2bf(oy) << 16);
    dest[(size_t)wid * 64 + lane] = o;
}

// ============ PERSISTENT fused 3x GRU chain, double-buffered stripes ============
// grid 512 (2 blocks/CU), 512 thr / 8 waves, 64 rows/stripe, grid-stride.
// LDS: lds[buf][mat][64*LROW] (bf16, padded rows). X and H1 arrive as bf16 tables
// (pure copies); next stripe's X/H1 prefetched during cell 2 and written to the
// alternate buffer after the stripe's last phase.
__global__ __launch_bounds__(512, 1) void gru3p_mfma_k(
        const unsigned* __restrict__ Xb,  // bf16x2 rows (x2b)
        const unsigned* __restrict__ H1b, // bf16x2 rows
        const float* __restrict__ H2, const float* __restrict__ H3,
        const short* __restrict__ w1i, const short* __restrict__ w1h,
        const short* __restrict__ w2i, const short* __restrict__ w2h,
        const short* __restrict__ w3i, const short* __restrict__ w3h,
        const float* __restrict__ bi1, const float* __restrict__ bh1,
        const float* __restrict__ bi2, const float* __restrict__ bh2,
        const float* __restrict__ bi3, const float* __restrict__ bh3,
        float* __restrict__ o1, float* __restrict__ o2, float* __restrict__ o3,
        int N, int nstripes) {
    __shared__ short lds[2][2][64 * LROW];    // ~68 KB
    int tid = threadIdx.x;
    int wave = tid >> 6, lane = tid & 63;
    int lr = lane & 15, kg = lane >> 4;
    int c0 = wave * 16;

    const short* wihs[3] = {w1i, w2i, w3i};
    const short* whhs[3] = {w1h, w2h, w3h};
    const float* bihs[3] = {bi1, bi2, bi3};
    const float* bhhs[3] = {bh1, bh2, bh3};
    float* outs[3] = {o1, o2, o3};

    short8_t bw[3][4], bu[3][4];
#define WLOADALL(wih_, whh_) { \
    _Pragma("unroll") \
    for (int g = 0; g < 3; g++) { \
        const short* wi = (wih_) + (size_t)(g * DH + c0 + lr) * DH + kg * 8; \
        const short* wh = (whh_) + (size_t)(g * DH + c0 + lr) * DH + kg * 8; \
        _Pragma("unroll") \
        for (int ks = 0; ks < 4; ks++) { \
            bw[g][ks] = *(const short8_t*)(wi + ks * 32); \
            bu[g][ks] = *(const short8_t*)(wh + ks * 32); \
        } \
    } }

    WLOADALL(w1i, w1h)

    int gcol = c0 + lr;
    int colb = gcol * 2;
    int srow = tid >> 3;               // T14 H2/H3 staging row
    int sq = tid & 7;                  // 16-col chunk
    int pmat = tid >> 8;               // bf16 staging: 0=X, 1=H1
    int prow = (tid & 255) >> 2;       // 0..63
    int pq = tid & 3;                  // 32-col (16 u32) chunk

    int s = blockIdx.x;
    if (s >= nstripes) return;

    // ---- initial stage: X,H1 bf16 pure copy into buf 0 ----
    {
        int grow = min(s * 64 + prow, N - 1);
        const uint4* src4 = (const uint4*)((pmat ? H1b : Xb) + (size_t)grow * 64 + pq * 16);
        uint4 a = src4[0], b = src4[1], c = src4[2], d = src4[3];
        char* dst = (char*)&lds[0][pmat][prow * LROW] + pq * 64;
        *(uint4*)(dst + 0)  = a;
        *(uint4*)(dst + 16) = b;
        *(uint4*)(dst + 32) = c;
        *(uint4*)(dst + 48) = d;
    }
    __syncthreads();

    int cur = 0;
    for (; s < nstripes; ) {
        int row0 = s * 64;
        int snext = s + gridDim.x;
        bool hasnext = snext < nstripes;
        short* ldsX = lds[cur][0];
        short* ldsH = lds[cur][1];
        short* nxtX = lds[cur ^ 1][0];
        short* nxtH = lds[cur ^ 1][1];
        uint4 px0, px1, px2, px3;      // next-stripe bf16 prefetch

#pragma unroll
        for (int cell = 0; cell < 3; cell++) {
            // ---- MFMA phase ----
            f32x4 aR[4], aZ[4], aI[4], aH[4];
#pragma unroll
            for (int rt = 0; rt < 4; rt++) {
                aR[rt] = (f32x4){0,0,0,0}; aZ[rt] = (f32x4){0,0,0,0};
                aI[rt] = (f32x4){0,0,0,0}; aH[rt] = (f32x4){0,0,0,0};
            }
#pragma unroll
            for (int rt = 0; rt < 4; rt++) {
                int r = rt * 16 + lr;
                const char* xrow = (const char*)&ldsX[r * LROW];
                const char* hrow = (const char*)&ldsH[r * LROW];
                short8_t xa[4], ha[4];
#pragma unroll
                for (int ks = 0; ks < 4; ks++) {
                    int boff = ks * 64 + kg * 16;
                    xa[ks] = *(const short8_t*)(xrow + boff);
                    ha[ks] = *(const short8_t*)(hrow + boff);
                }
#pragma unroll
                for (int ks = 0; ks < 4; ks++) {
                    aR[rt] = __builtin_amdgcn_mfma_f32_16x16x32_bf16(xa[ks], bw[0][ks], aR[rt], 0, 0, 0);
                    aR[rt] = __builtin_amdgcn_mfma_f32_16x16x32_bf16(ha[ks], bu[0][ks], aR[rt], 0, 0, 0);
                    aZ[rt] = __builtin_amdgcn_mfma_f32_16x16x32_bf16(xa[ks], bw[1][ks], aZ[rt], 0, 0, 0);
                    aZ[rt] = __builtin_amdgcn_mfma_f32_16x16x32_bf16(ha[ks], bu[1][ks], aZ[rt], 0, 0, 0);
                    aI[rt] = __builtin_amdgcn_mfma_f32_16x16x32_bf16(xa[ks], bw[2][ks], aI[rt], 0, 0, 0);
                    aH[rt] = __builtin_amdgcn_mfma_f32_16x16x32_bf16(ha[ks], bu[2][ks], aH[rt], 0, 0, 0);
                }
            }

            // ---- async loads covered by epilogue ----
            float4 hs0, hs1, hs2, hs3;
            if (cell < 2) {            // T14: next-cell H (fp32)
                int grow = min(row0 + srow, N - 1);
                const float* src = (cell == 0 ? H2 : H3) + (size_t)grow * DH + sq * 16;
                hs0 = *(const float4*)(src + 0);
                hs1 = *(const float4*)(src + 4);
                hs2 = *(const float4*)(src + 8);
                hs3 = *(const float4*)(src + 12);
            } else if (hasnext) {      // next-stripe X,H1 (bf16 copy)
                int grow = min(snext * 64 + prow, N - 1);
                const uint4* src4 = (const uint4*)((pmat ? H1b : Xb) + (size_t)grow * 64 + pq * 16);
                px0 = src4[0]; px1 = src4[1]; px2 = src4[2]; px3 = src4[3];
            }

            // ---- epilogue ----
            const float* bih = bihs[cell];
            const float* bhh = bhhs[cell];
            float br = bih[gcol], bz = bih[DH + gcol], bn = bih[2 * DH + gcol];
            float cr = bhh[gcol], cz = bhh[DH + gcol], cn = bhh[2 * DH + gcol];
            float* outp = outs[cell];
            short hb[4][4];
#pragma unroll
            for (int rt = 0; rt < 4; rt++) {
#pragma unroll
                for (int j = 0; j < 4; j++) {
                    int r = rt * 16 + kg * 4 + j;
                    float hv = bf2f(*(const unsigned short*)((const char*)&ldsH[r * LROW] + colb));
                    float rr = sigm(aR[rt][j] + br + cr);
                    float zz = sigm(aZ[rt][j] + bz + cz);
                    float nn = tanh_f(aI[rt][j] + bn + rr * (aH[rt][j] + cn));
                    float ov = (1.f - zz) * nn + zz * hv;
                    int grow = row0 + r;
                    if (grow < N) outp[(size_t)grow * DH + gcol] = ov;
                    hb[rt][j] = f2bf(ov);
                }
            }

            // ---- weight prefetch ----
            if (cell < 2) {
                WLOADALL(wihs[cell + 1], whhs[cell + 1])
            } else if (hasnext) {
                WLOADALL(w1i, w1h)
            }

            if (cell < 2) {
                __syncthreads();   // done reading ldsX/ldsH
                // h_next -> X slot
#pragma unroll
                for (int rt = 0; rt < 4; rt++) {
#pragma unroll
                    for (int j = 0; j < 4; j++) {
                        int r = rt * 16 + kg * 4 + j;
                        *(short*)((char*)&ldsX[r * LROW] + colb) = hb[rt][j];
                    }
                }
                // staged H_{cell+2} -> H slot
                {
                    char* dst = (char*)&ldsH[srow * LROW] + sq * 32;
                    *(short8_t*)(dst) = cvt8v(hs0, hs1);
                    *(short8_t*)(dst + 16) = cvt8v(hs2, hs3);
                }
                __syncthreads();
            } else if (hasnext) {
                // write prefetched next-stripe X,H1 into alternate buffer
                // (safe without a preceding barrier: alternate buffer was last
                //  read a full stripe ago, behind two barriers)
                char* dst = (char*)&(pmat ? nxtH : nxtX)[prow * LROW] + pq * 64;
                *(uint4*)(dst + 0)  = px0;
                *(uint4*)(dst + 16) = px1;
                *(uint4*)(dst + 32) = px2;
                *(uint4*)(dst + 48) = px3;
                __syncthreads();
            }
        }
        cur ^= 1;
        s = snext;
    }
#undef WLOADALL
}

extern "C" void kernel_launch(void* const* d_in, const int* in_sizes, int n_in,
                              void* d_out, int out_size, void* d_ws, size_t ws_size,
                              hipStream_t stream) {
    const float* x    = (const float*)d_in[0];
    const int*   ei   = (const int*)d_in[1];
    const float* h1   = (const float*)d_in[2];
    const float* h2   = (const float*)d_in[3];
    const float* h3   = (const float*)d_in[4];
    const float* g1w  = (const float*)d_in[5];
    const float* g1b  = (const float*)d_in[6];
    const float* g2w  = (const float*)d_in[7];
    const float* g2b  = (const float*)d_in[8];
    const float* wih1 = (const float*)d_in[9];
    const float* whh1 = (const float*)d_in[10];
    const float* bih1 = (const float*)d_in[11];
    const float* bhh1 = (const float*)d_in[12];
    const float* wih2 = (const float*)d_in[13];
    const float* whh2 = (const float*)d_in[14];
    const float* bih2 = (const float*)d_in[15];
    const float* bhh2 = (const float*)d_in[16];
    const float* wih3 = (const float*)d_in[17];
    const float* whh3 = (const float*)d_in[18];
    const float* bih3 = (const float*)d_in[19];
    const float* bhh3 = (const float*)d_in[20];

    int N = in_sizes[0] / DH;
    int E = in_sizes[1] / 2;
    int B = (N + SCB - 1) / SCB;
    int nstripes = (N + 127) / 128;
    int nblk64 = (N + 63) / 64;
    int span = (N + 7) / 8;
    int chunkE = (E + NCHUNK - 1) / NCHUNK;

    char* wsp = (char*)d_ws;
    auto alloc = [&](size_t bytes) -> char* {
        char* p = wsp;
        wsp += (bytes + 63) & ~(size_t)63;
        return p;
    };
    unsigned* cnt = (unsigned*)alloc((size_t)N * 4);
    int* offs     = (int*)alloc(((size_t)N + 1) * 4);
    int* cur      = (int*)alloc((size_t)N * 4);
    float* dinv   = (float*)alloc((size_t)N * 4);
    unsigned* bsum= (unsigned*)alloc(((size_t)B + 1) * 4);
    int* csr_src  = (int*)alloc((size_t)E * 4);
    unsigned char* xq = (unsigned char*)alloc((size_t)N * DH);   // fp8 pre-scaled table
    unsigned* x2b = (unsigned*)alloc((size_t)N * DH * 2);        // bf16x2 activations
    unsigned* h1b = (unsigned*)alloc((size_t)N * DH * 2);        // bf16x2 h1
    short* w1t    = (short*)alloc((size_t)DH * DH * 2);
    short* w2t    = (short*)alloc((size_t)DH * DH * 2);
    const int WN = 3 * DH * DH;      // 49152
    short* wbAll  = (short*)alloc((size_t)6 * WN * 2);
    short* wb[6];
    for (int i = 0; i < 6; i++) wb[i] = wbAll + (size_t)i * WN;

    float* out  = (float*)d_out;
    float* h1n  = out;
    float* h2n  = out + (size_t)N * DH;
    float* h3n  = out + 2 * (size_t)N * DH;

    // ---- weight/activation prep (bf16) ----
    f2bf6_k<<<(6 * WN + 255) / 256, 256, 0, stream>>>(wih1, whh1, wih2, whh2, wih3, whh3, wbAll, WN);
    transpose_bf2_k<<<(2 * DH * DH + 255) / 256, 256, 0, stream>>>(g1w, g2w, w1t, w2t);
    long long n2 = (long long)N * DH / 2;
    h1bf_k<<<(int)((n2 + 255) / 256), 256, 0, stream>>>(h1, h1b, n2);

    // ---- CSR build (per call; deterministic), XCD-partitioned ----
    hipMemsetAsync(cnt, 0, (size_t)N * 4, stream);
    deg2_k<<<8 * NCHUNK, 256, 0, stream>>>(ei, E, cnt, span, chunkE);
    scan1_k<<<B, 256, 0, stream>>>(cnt, N, offs, bsum);
    scan2_k<<<1, 1024, 0, stream>>>(bsum, B);
    scan3_k<<<(N + 255) / 256, 256, 0, stream>>>(offs, cur, dinv, cnt, bsum, N, B);
    fill2_k<<<8 * NCHUNK, 256, 0, stream>>>(ei, E, cur, csr_src, span, chunkE);

    int gblocks = (N + 3) / 4;

    // ---- GCN layer 1 ----
    gemm_mfma_k<<<nstripes, 256, 0, stream>>>(x, w1t, dinv, xq, N);
    gather_k<<<gblocks, 256, 0, stream>>>(csr_src, offs, dinv, (const unsigned short*)xq, g1b, x2b, N);

    // ---- GCN layer 2 (bf16 A) ----
    gemm_mfma_bf_k<<<nstripes, 256, 0, stream>>>((const short*)x2b, w2t, dinv, xq, N);
    gather_k<<<gblocks, 256, 0, stream>>>(csr_src, offs, dinv, (const unsigned short*)xq, g2b, x2b, N);

    // ---- fused persistent GRU chain ----
    gru3p_mfma_k<<<512, 512, 0, stream>>>(x2b, h1b, h2, h3,
                                          wb[0], wb[1], wb[2], wb[3], wb[4], wb[5],
                                          bih1, bhh1, bih2, bhh2, bih3, bhh3,
                                          h1n, h2n, h3n, N, nblk64);
}

// Round 19
// 530.077 us; speedup vs baseline: 1.2953x; 1.2953x over previous
//
#include <hip/hip_runtime.h>
#include <hip/hip_bf16.h>

#define DH 128          // feature dim (D_IN == H == 128)
#define SCB 1024        // scan elements per block
#define NCHUNK 256      // edge chunks for XCD-partitioned CSR build
#define LROW 136        // LDS row stride in shorts (256B + 16B pad)

typedef __attribute__((ext_vector_type(8))) short short8_t;
typedef __attribute__((ext_vector_type(4))) float f32x4;
typedef __attribute__((ext_vector_type(2))) float f32x2;

static __device__ __forceinline__ short f2bf(float f) {
    union { float f; unsigned u; } v; v.f = f;
    unsigned r = v.u + 0x7fffu + ((v.u >> 16) & 1u);   // RNE
    return (short)(r >> 16);
}

static __device__ __forceinline__ float bf2f(unsigned short b) {
    union { unsigned u; float f; } v; v.u = ((unsigned)b) << 16;
    return v.f;
}

static __device__ __forceinline__ short8_t cvt8(const float* p) {
    float4 a0 = *(const float4*)p;
    float4 a1 = *(const float4*)(p + 4);
    short8_t t;
    t[0] = f2bf(a0.x); t[1] = f2bf(a0.y); t[2] = f2bf(a0.z); t[3] = f2bf(a0.w);
    t[4] = f2bf(a1.x); t[5] = f2bf(a1.y); t[6] = f2bf(a1.z); t[7] = f2bf(a1.w);
    return t;
}

static __device__ __forceinline__ short8_t cvt8v(float4 a0, float4 a1) {
    short8_t t;
    t[0] = f2bf(a0.x); t[1] = f2bf(a0.y); t[2] = f2bf(a0.z); t[3] = f2bf(a0.w);
    t[4] = f2bf(a1.x); t[5] = f2bf(a1.y); t[6] = f2bf(a1.z); t[7] = f2bf(a1.w);
    return t;
}

static __device__ __forceinline__ float sigm(float x) {
    return __builtin_amdgcn_rcpf(1.f + __expf(-x));
}
static __device__ __forceinline__ float tanh_f(float x) {
    return 1.f - 2.f * __builtin_amdgcn_rcpf(__expf(2.f * x) + 1.f);
}

// ---------------- degree histogram, XCD-partitioned ----------------
__global__ __launch_bounds__(256) void deg2_k(const int* __restrict__ ei, int E,
                                              unsigned* __restrict__ cnt, int span, int chunkE) {
    int r = blockIdx.x & 7;
    int c = blockIdx.x >> 3;
    int lo = r * span, hi = lo + span;
    long long e0 = (long long)c * chunkE;
    long long e1 = e0 + chunkE; if (e1 > E) e1 = E;
    for (long long e = e0 + threadIdx.x; e < e1; e += 256) {
        int d = ei[E + e];
        if (d >= lo && d < hi) atomicAdd(&cnt[d], 1u);
    }
}

// ---------------- 3-phase grid-parallel exclusive scan ----------------
__global__ __launch_bounds__(256) void scan1_k(const unsigned* __restrict__ cnt, int N,
                                               int* __restrict__ offs, unsigned* __restrict__ bsum) {
    __shared__ unsigned s[256];
    int t = threadIdx.x;
    int i0 = blockIdx.x * SCB + t * 4;
    unsigned v0 = (i0 + 0 < N) ? cnt[i0 + 0] : 0u;
    unsigned v1 = (i0 + 1 < N) ? cnt[i0 + 1] : 0u;
    unsigned v2 = (i0 + 2 < N) ? cnt[i0 + 2] : 0u;
    unsigned v3 = (i0 + 3 < N) ? cnt[i0 + 3] : 0u;
    unsigned ts = v0 + v1 + v2 + v3;
    s[t] = ts;
    __syncthreads();
    for (int off = 1; off < 256; off <<= 1) {
        unsigned u = (t >= off) ? s[t - off] : 0u;
        __syncthreads();
        s[t] += u;
        __syncthreads();
    }
    unsigned ex = s[t] - ts;
    if (i0 + 0 < N) offs[i0 + 0] = (int)ex;
    if (i0 + 1 < N) offs[i0 + 1] = (int)(ex + v0);
    if (i0 + 2 < N) offs[i0 + 2] = (int)(ex + v0 + v1);
    if (i0 + 3 < N) offs[i0 + 3] = (int)(ex + v0 + v1 + v2);
    if (t == 255) bsum[blockIdx.x] = s[255];
}

__global__ __launch_bounds__(1024) void scan2_k(unsigned* __restrict__ bsum, int B) {
    __shared__ unsigned s[1024];
    int t = threadIdx.x;
    unsigned v = (t < B) ? bsum[t] : 0u;
    s[t] = v;
    __syncthreads();
    for (int off = 1; off < 1024; off <<= 1) {
        unsigned u = (t >= off) ? s[t - off] : 0u;
        __syncthreads();
        s[t] += u;
        __syncthreads();
    }
    if (t < B) bsum[t] = s[t] - v;
    if (t == 0) bsum[B] = s[1023];
}

__global__ void scan3_k(int* __restrict__ offs, int* __restrict__ cur,
                        float* __restrict__ dinv, const unsigned* __restrict__ cnt,
                        const unsigned* __restrict__ bsum, int N, int B) {
    int i = blockIdx.x * 256 + threadIdx.x;
    if (i < N) {
        int v = offs[i] + (int)bsum[i >> 10];
        offs[i] = v;
        cur[i] = v;
        dinv[i] = rsqrtf((float)cnt[i] + 1.0f);
    }
    if (i == 0) offs[N] = (int)bsum[B];
}

// ---------------- CSR fill, XCD-partitioned ----------------
__global__ __launch_bounds__(256) void fill2_k(const int* __restrict__ ei, int E,
                                               int* __restrict__ cur, int* __restrict__ csr_src,
                                               int span, int chunkE) {
    int r = blockIdx.x & 7;
    int c = blockIdx.x >> 3;
    int lo = r * span, hi = lo + span;
    long long e0 = (long long)c * chunkE;
    long long e1 = e0 + chunkE; if (e1 > E) e1 = E;
    for (long long e = e0 + threadIdx.x; e < e1; e += 256) {
        int d = ei[E + e];
        if (d >= lo && d < hi) {
            int pos = atomicAdd(&cur[d], 1);
            csr_src[pos] = ei[e];
        }
    }
}

// ---------------- weight prep ----------------
__global__ void f2bf6_k(const float* __restrict__ s0, const float* __restrict__ s1,
                        const float* __restrict__ s2, const float* __restrict__ s3,
                        const float* __restrict__ s4, const float* __restrict__ s5,
                        short* __restrict__ dst, int WN) {
    int i = blockIdx.x * 256 + threadIdx.x;
    if (i >= 6 * WN) return;
    int b = i / WN, r = i - b * WN;
    const float* srcs[6] = {s0, s1, s2, s3, s4, s5};
    dst[i] = f2bf(srcs[b][r]);
}

__global__ void transpose_bf2_k(const float* __restrict__ sa, const float* __restrict__ sb,
                                short* __restrict__ da, short* __restrict__ db) {
    int i = blockIdx.x * 256 + threadIdx.x;   // 2*16384
    int m = i >> 14;
    int j = i & 16383;
    int c = j >> 7, k = j & 127;
    const float* s = m ? sb : sa;
    short* d = m ? db : da;
    d[j] = f2bf(s[k * DH + c]);
}

// h1 fp32 -> packed bf16x2 table
__global__ void h1bf_k(const float* __restrict__ src, unsigned* __restrict__ dst, long long n2) {
    long long i = (long long)blockIdx.x * 256 + threadIdx.x;   // one u32 (2 floats) per thread
    if (i < n2) {
        float2 v = ((const float2*)src)[i];
        dst[i] = (unsigned)(unsigned short)f2bf(v.x) | ((unsigned)(unsigned short)f2bf(v.y) << 16);
    }
}

// ================= MFMA GEMM (fp32 A) -> pre-scaled fp8 table (HW cvt) ===========
__global__ __launch_bounds__(256, 4) void gemm_mfma_k(const float* __restrict__ A,
                                                      const short* __restrict__ Wt,
                                                      const float* __restrict__ dinv,
                                                      unsigned char* __restrict__ C, int N) {
    int tid = threadIdx.x;
    int wave = tid >> 6, lane = tid & 63;
    int lr = lane & 15, kg = lane >> 4;

    int row0 = blockIdx.x * 128 + wave * 32;
    int ar0 = min(row0 + lr, N - 1);
    int ar1 = min(row0 + 16 + lr, N - 1);
    const float* a0p = A + (size_t)ar0 * DH;
    const float* a1p = A + (size_t)ar1 * DH;
    short8_t af[2][4];
#pragma unroll
    for (int ks = 0; ks < 4; ks++) {
        af[0][ks] = cvt8(a0p + ks * 32 + kg * 8);
        af[1][ks] = cvt8(a1p + ks * 32 + kg * 8);
    }

    float di0[4], di1[4];
#pragma unroll
    for (int j = 0; j < 4; j++) {
        di0[j] = dinv[min(row0 + kg * 4 + j, N - 1)];
        di1[j] = dinv[min(row0 + 16 + kg * 4 + j, N - 1)];
    }

    short8_t bt[3][4];
#define GLOADW(slot, t) { \
    const short* wp = Wt + (size_t)((t) * 16 + lr) * DH + kg * 8; \
    bt[slot][0] = *(const short8_t*)(wp); \
    bt[slot][1] = *(const short8_t*)(wp + 32); \
    bt[slot][2] = *(const short8_t*)(wp + 64); \
    bt[slot][3] = *(const short8_t*)(wp + 96); }

    GLOADW(0, 0)
    GLOADW(1, 1)
#pragma unroll
    for (int t = 0; t < 8; t++) {
        if (t < 6) GLOADW((t + 2) % 3, t + 2)
        f32x4 acc0 = {0.f, 0.f, 0.f, 0.f};
        f32x4 acc1 = {0.f, 0.f, 0.f, 0.f};
#pragma unroll
        for (int ks = 0; ks < 4; ks++) {
            acc0 = __builtin_amdgcn_mfma_f32_16x16x32_bf16(af[0][ks], bt[t % 3][ks], acc0, 0, 0, 0);
            acc1 = __builtin_amdgcn_mfma_f32_16x16x32_bf16(af[1][ks], bt[t % 3][ks], acc1, 0, 0, 0);
        }
        int col = t * 16 + lr;
#pragma unroll
        for (int j = 0; j < 4; j++) {
            int g0 = row0 + kg * 4 + j;
            int g1 = row0 + 16 + kg * 4 + j;
            float v0 = acc0[j] * di0[j];
            float v1 = acc1[j] * di1[j];
            if (g0 < N) C[(size_t)g0 * DH + col] =
                (unsigned char)__builtin_amdgcn_cvt_pk_fp8_f32(v0, v0, 0u, false);
            if (g1 < N) C[(size_t)g1 * DH + col] =
                (unsigned char)__builtin_amdgcn_cvt_pk_fp8_f32(v1, v1, 0u, false);
        }
    }
#undef GLOADW
}

// ================= MFMA GEMM (bf16 A) -> pre-scaled fp8 table ===========
__global__ __launch_bounds__(256, 4) void gemm_mfma_bf_k(const short* __restrict__ A, // bf16 rows
                                                         const short* __restrict__ Wt,
                                                         const float* __restrict__ dinv,
                                                         unsigned char* __restrict__ C, int N) {
    int tid = threadIdx.x;
    int wave = tid >> 6, lane = tid & 63;
    int lr = lane & 15, kg = lane >> 4;

    int row0 = blockIdx.x * 128 + wave * 32;
    int ar0 = min(row0 + lr, N - 1);
    int ar1 = min(row0 + 16 + lr, N - 1);
    const short* a0p = A + (size_t)ar0 * DH;
    const short* a1p = A + (size_t)ar1 * DH;
    short8_t af[2][4];
#pragma unroll
    for (int ks = 0; ks < 4; ks++) {
        af[0][ks] = *(const short8_t*)(a0p + ks * 32 + kg * 8);
        af[1][ks] = *(const short8_t*)(a1p + ks * 32 + kg * 8);
    }

    float di0[4], di1[4];
#pragma unroll
    for (int j = 0; j < 4; j++) {
        di0[j] = dinv[min(row0 + kg * 4 + j, N - 1)];
        di1[j] = dinv[min(row0 + 16 + kg * 4 + j, N - 1)];
    }

    short8_t bt[3][4];
#define GLOADW(slot, t) { \
    const short* wp = Wt + (size_t)((t) * 16 + lr) * DH + kg * 8; \
    bt[slot][0] = *(const short8_t*)(wp); \
    bt[slot][1] = *(const short8_t*)(wp + 32); \
    bt[slot][2] = *(const short8_t*)(wp + 64); \
    bt[slot][3] = *(const short8_t*)(wp + 96); }

    GLOADW(0, 0)
    GLOADW(1, 1)
#pragma unroll
    for (int t = 0; t < 8; t++) {
        if (t < 6) GLOADW((t + 2) % 3, t + 2)
        f32x4 acc0 = {0.f, 0.f, 0.f, 0.f};
        f32x4 acc1 = {0.f, 0.f, 0.f, 0.f};
#pragma unroll
        for (int ks = 0; ks < 4; ks++) {
            acc0 = __builtin_amdgcn_mfma_f32_16x16x32_bf16(af[0][ks], bt[t % 3][ks], acc0, 0, 0, 0);
            acc1 = __builtin_amdgcn_mfma_f32_16x16x32_bf16(af[1][ks], bt[t % 3][ks], acc1, 0, 0, 0);
        }
        int col = t * 16 + lr;
#pragma unroll
        for (int j = 0; j < 4; j++) {
            int g0 = row0 + kg * 4 + j;
            int g1 = row0 + 16 + kg * 4 + j;
            float v0 = acc0[j] * di0[j];
            float v1 = acc1[j] * di1[j];
            if (g0 < N) C[(size_t)g0 * DH + col] =
                (unsigned char)__builtin_amdgcn_cvt_pk_fp8_f32(v0, v0, 0u, false);
            if (g1 < N) C[(size_t)g1 * DH + col] =
                (unsigned char)__builtin_amdgcn_cvt_pk_fp8_f32(v1, v1, 0u, false);
        }
    }
#undef GLOADW
}

// ---------------- gather: fp8 table in, packed bf16 out ----------
__global__ __launch_bounds__(256) void gather_k(const int* __restrict__ csr_src,
                                                const int* __restrict__ offs,
                                                const float* __restrict__ dinv,
                                                const unsigned short* __restrict__ xq2, // 2 fp8/ushort
                                                const float* __restrict__ bias,
                                                unsigned* __restrict__ dest, int N) {
    int wid = blockIdx.x * 4 + (threadIdx.x >> 6);
    if (wid >= N) return;
    int lane = threadIdx.x & 63;
    int j = offs[wid];
    int end = offs[wid + 1];
    float dd = dinv[wid];

    f32x2 f0 = __builtin_amdgcn_cvt_pk_f32_fp8((unsigned)xq2[(size_t)wid * 64 + lane], false);
    float ax = f0[0];
    float ay = f0[1];

#define ACC(w) { f32x2 f_ = __builtin_amdgcn_cvt_pk_f32_fp8((unsigned)(w), false); \
                 ax += f_[0]; ay += f_[1]; }

    if (j + 4 <= end) {
        int a0 = csr_src[j], a1 = csr_src[j + 1], a2 = csr_src[j + 2], a3 = csr_src[j + 3];
        j += 4;
        for (; j + 4 <= end; j += 4) {
            unsigned w0 = xq2[(size_t)a0 * 64 + lane];
            unsigned w1 = xq2[(size_t)a1 * 64 + lane];
            unsigned w2 = xq2[(size_t)a2 * 64 + lane];
            unsigned w3 = xq2[(size_t)a3 * 64 + lane];
            a0 = csr_src[j]; a1 = csr_src[j + 1]; a2 = csr_src[j + 2]; a3 = csr_src[j + 3];
            ACC(w0) ACC(w1) ACC(w2) ACC(w3)
        }
        unsigned w0 = xq2[(size_t)a0 * 64 + lane];
        unsigned w1 = xq2[(size_t)a1 * 64 + lane];
        unsigned w2 = xq2[(size_t)a2 * 64 + lane];
        unsigned w3 = xq2[(size_t)a3 * 64 + lane];
        ACC(w0) ACC(w1) ACC(w2) ACC(w3)
    }
    for (; j < end; ++j) {
        unsigned w = xq2[(size_t)csr_src[j] * 64 + lane];
        ACC(w)
    }
#undef ACC

    float2 b2 = ((const float2*)bias)[lane];
    float ox = fmaxf(fmaf(dd, ax, b2.x), 0.f);
    float oy = fmaxf(fmaf(dd, ay, b2.y), 0.f);
    unsigned o = (unsigned)(unsigned short)f2bf(ox) | ((unsigned)(unsigned short)f2bf(oy) << 16);
    dest[(size_t)wid * 64 + lane] = o;
}

// ============ FUSED 3x GRU chain, 2-slot LDS + async JIT H staging (R17 struct) =====
// 512 thr / 8 waves, 64 rows/block. slot0 = X/h_next, slot1 = current H.
// X, H1 arrive as packed bf16 tables -> initial stage is a pure 16B copy.
__global__ __launch_bounds__(512, 1) void gru3_mfma_k(
        const unsigned* __restrict__ Xb,  // bf16x2 rows
        const unsigned* __restrict__ H1b, // bf16x2 rows
        const float* __restrict__ H2, const float* __restrict__ H3,
        const short* __restrict__ w1i, const short* __restrict__ w1h,
        const short* __restrict__ w2i, const short* __restrict__ w2h,
        const short* __restrict__ w3i, const short* __restrict__ w3h,
        const float* __restrict__ bi1, const float* __restrict__ bh1,
        const float* __restrict__ bi2, const float* __restrict__ bh2,
        const float* __restrict__ bi3, const float* __restrict__ bh3,
        float* __restrict__ o1, float* __restrict__ o2, float* __restrict__ o3,
        int N) {
    __shared__ short lds[2][64 * LROW];    // ~34 KB
    int tid = threadIdx.x;
    int row0 = blockIdx.x * 64;
    int wave = tid >> 6, lane = tid & 63;
    int lr = lane & 15, kg = lane >> 4;
    int c0 = wave * 16;

    const short* wihs[3] = {w1i, w2i, w3i};
    const short* whhs[3] = {w1h, w2h, w3h};
    const float* bihs[3] = {bi1, bi2, bi3};
    const float* bhhs[3] = {bh1, bh2, bh3};
    float* outs[3] = {o1, o2, o3};

    short8_t bw[3][4], bu[3][4];   // weight frags for CURRENT cell
#define WLOADALL(wih_, whh_) { \
    _Pragma("unroll") \
    for (int g = 0; g < 3; g++) { \
        const short* wi = (wih_) + (size_t)(g * DH + c0 + lr) * DH + kg * 8; \
        const short* wh = (whh_) + (size_t)(g * DH + c0 + lr) * DH + kg * 8; \
        _Pragma("unroll") \
        for (int ks = 0; ks < 4; ks++) { \
            bw[g][ks] = *(const short8_t*)(wi + ks * 32); \
            bu[g][ks] = *(const short8_t*)(wh + ks * 32); \
        } \
    } }

    WLOADALL(w1i, w1h)

    // ---- initial stage: X,H1 packed-bf16 pure copy ----
    {
        int mat = tid >> 8;            // 0=X, 1=H1
        int r = (tid & 255) >> 2;      // 0..63
        int q = tid & 3;               // 32-col (16 u32) chunk
        int grow = min(row0 + r, N - 1);
        const uint4* src4 = (const uint4*)((mat ? H1b : Xb) + (size_t)grow * 64 + q * 16);
        uint4 a = src4[0], b = src4[1], c = src4[2], d = src4[3];
        char* dst = (char*)&lds[mat][r * LROW] + q * 64;
        *(uint4*)(dst + 0)  = a;
        *(uint4*)(dst + 16) = b;
        *(uint4*)(dst + 32) = c;
        *(uint4*)(dst + 48) = d;
    }
    __syncthreads();

    int gcol = c0 + lr;
    int colb = gcol * 2;               // byte offset of this lane's column
    int srow = tid >> 3;               // staging row (0..63)
    int sq = tid & 7;                  // staging 16-col chunk

#pragma unroll
    for (int cell = 0; cell < 3; cell++) {
        // ---- MFMA phase (slot0 = x, slot1 = h) ----
        f32x4 aR[4], aZ[4], aI[4], aH[4];
#pragma unroll
        for (int rt = 0; rt < 4; rt++) {
            aR[rt] = (f32x4){0,0,0,0}; aZ[rt] = (f32x4){0,0,0,0};
            aI[rt] = (f32x4){0,0,0,0}; aH[rt] = (f32x4){0,0,0,0};
        }
#pragma unroll
        for (int rt = 0; rt < 4; rt++) {
            int r = rt * 16 + lr;
            const char* xrow = (const char*)&lds[0][r * LROW];
            const char* hrow = (const char*)&lds[1][r * LROW];
            short8_t xa[4], ha[4];
#pragma unroll
            for (int ks = 0; ks < 4; ks++) {
                int boff = ks * 64 + kg * 16;
                xa[ks] = *(const short8_t*)(xrow + boff);
                ha[ks] = *(const short8_t*)(hrow + boff);
            }
#pragma unroll
            for (int ks = 0; ks < 4; ks++) {
                aR[rt] = __builtin_amdgcn_mfma_f32_16x16x32_bf16(xa[ks], bw[0][ks], aR[rt], 0, 0, 0);
                aR[rt] = __builtin_amdgcn_mfma_f32_16x16x32_bf16(ha[ks], bu[0][ks], aR[rt], 0, 0, 0);
                aZ[rt] = __builtin_amdgcn_mfma_f32_16x16x32_bf16(xa[ks], bw[1][ks], aZ[rt], 0, 0, 0);
                aZ[rt] = __builtin_amdgcn_mfma_f32_16x16x32_bf16(ha[ks], bu[1][ks], aZ[rt], 0, 0, 0);
                aI[rt] = __builtin_amdgcn_mfma_f32_16x16x32_bf16(xa[ks], bw[2][ks], aI[rt], 0, 0, 0);
                aH[rt] = __builtin_amdgcn_mfma_f32_16x16x32_bf16(ha[ks], bu[2][ks], aH[rt], 0, 0, 0);
            }
        }

        // ---- T14: issue next-H global loads NOW; epilogue covers the latency ----
        float4 hs0, hs1, hs2, hs3;
        if (cell < 2) {
            int grow = min(row0 + srow, N - 1);
            const float* src = (cell == 0 ? H2 : H3) + (size_t)grow * DH + sq * 16;
            hs0 = *(const float4*)(src + 0);
            hs1 = *(const float4*)(src + 4);
            hs2 = *(const float4*)(src + 8);
            hs3 = *(const float4*)(src + 12);
        }

        // ---- epilogue (hv from slot1) ----
        const float* bih = bihs[cell];
        const float* bhh = bhhs[cell];
        float br = bih[gcol], bz = bih[DH + gcol], bn = bih[2 * DH + gcol];
        float cr = bhh[gcol], cz = bhh[DH + gcol], cn = bhh[2 * DH + gcol];
        float* outp = outs[cell];
        short hb[4][4];                 // bf16 h_next for LDS write-back
#pragma unroll
        for (int rt = 0; rt < 4; rt++) {
#pragma unroll
            for (int j = 0; j < 4; j++) {
                int r = rt * 16 + kg * 4 + j;
                float hv = bf2f(*(const unsigned short*)((const char*)&lds[1][r * LROW] + colb));
                float rr = sigm(aR[rt][j] + br + cr);
                float zz = sigm(aZ[rt][j] + bz + cz);
                float nn = tanh_f(aI[rt][j] + bn + rr * (aH[rt][j] + cn));
                float ov = (1.f - zz) * nn + zz * hv;
                int grow = row0 + r;
                if (grow < N) outp[(size_t)grow * DH + gcol] = ov;
                hb[rt][j] = f2bf(ov);
            }
        }

        // ---- prefetch next cell's weights ----
        if (cell < 2) {
            WLOADALL(wihs[cell + 1], whhs[cell + 1])
        }

        __syncthreads();   // everyone done READING slot0/slot1

        if (cell < 2) {
            // write h_next (bf16) into slot0
#pragma unroll
            for (int rt = 0; rt < 4; rt++) {
#pragma unroll
                for (int j = 0; j < 4; j++) {
                    int r = rt * 16 + kg * 4 + j;
                    *(short*)((char*)&lds[0][r * LROW] + colb) = hb[rt][j];
                }
            }
            // write staged H_{c+1} (already in registers) into slot1
            {
                char* dst = (char*)&lds[1][srow * LROW] + sq * 32;
                *(short8_t*)(dst) = cvt8v(hs0, hs1);
                *(short8_t*)(dst + 16) = cvt8v(hs2, hs3);
            }
            __syncthreads();
        }
    }
#undef WLOADALL
}

extern "C" void kernel_launch(void* const* d_in, const int* in_sizes, int n_in,
                              void* d_out, int out_size, void* d_ws, size_t ws_size,
                              hipStream_t stream) {
    const float* x    = (const float*)d_in[0];
    const int*   ei   = (const int*)d_in[1];
    const float* h1   = (const float*)d_in[2];
    const float* h2   = (const float*)d_in[3];
    const float* h3   = (const float*)d_in[4];
    const float* g1w  = (const float*)d_in[5];
    const float* g1b  = (const float*)d_in[6];
    const float* g2w  = (const float*)d_in[7];
    const float* g2b  = (const float*)d_in[8];
    const float* wih1 = (const float*)d_in[9];
    const float* whh1 = (const float*)d_in[10];
    const float* bih1 = (const float*)d_in[11];
    const float* bhh1 = (const float*)d_in[12];
    const float* wih2 = (const float*)d_in[13];
    const float* whh2 = (const float*)d_in[14];
    const float* bih2 = (const float*)d_in[15];
    const float* bhh2 = (const float*)d_in[16];
    const float* wih3 = (const float*)d_in[17];
    const float* whh3 = (const float*)d_in[18];
    const float* bih3 = (const float*)d_in[19];
    const float* bhh3 = (const float*)d_in[20];

    int N = in_sizes[0] / DH;
    int E = in_sizes[1] / 2;
    int B = (N + SCB - 1) / SCB;
    int nstripes = (N + 127) / 128;
    int nblk64 = (N + 63) / 64;
    int span = (N + 7) / 8;
    int chunkE = (E + NCHUNK - 1) / NCHUNK;

    char* wsp = (char*)d_ws;
    auto alloc = [&](size_t bytes) -> char* {
        char* p = wsp;
        wsp += (bytes + 63) & ~(size_t)63;
        return p;
    };
    unsigned* cnt = (unsigned*)alloc((size_t)N * 4);
    int* offs     = (int*)alloc(((size_t)N + 1) * 4);
    int* cur      = (int*)alloc((size_t)N * 4);
    float* dinv   = (float*)alloc((size_t)N * 4);
    unsigned* bsum= (unsigned*)alloc(((size_t)B + 1) * 4);
    int* csr_src  = (int*)alloc((size_t)E * 4);
    unsigned char* xq = (unsigned char*)alloc((size_t)N * DH);   // fp8 pre-scaled table
    unsigned* x2b = (unsigned*)alloc((size_t)N * DH * 2);        // bf16x2 activations
    unsigned* h1b = (unsigned*)alloc((size_t)N * DH * 2);        // bf16x2 h1
    short* w1t    = (short*)alloc((size_t)DH * DH * 2);
    short* w2t    = (short*)alloc((size_t)DH * DH * 2);
    const int WN = 3 * DH * DH;      // 49152
    short* wbAll  = (short*)alloc((size_t)6 * WN * 2);
    short* wb[6];
    for (int i = 0; i < 6; i++) wb[i] = wbAll + (size_t)i * WN;

    float* out  = (float*)d_out;
    float* h1n  = out;
    float* h2n  = out + (size_t)N * DH;
    float* h3n  = out + 2 * (size_t)N * DH;

    // ---- weight/activation prep (bf16) ----
    f2bf6_k<<<(6 * WN + 255) / 256, 256, 0, stream>>>(wih1, whh1, wih2, whh2, wih3, whh3, wbAll, WN);
    transpose_bf2_k<<<(2 * DH * DH + 255) / 256, 256, 0, stream>>>(g1w, g2w, w1t, w2t);
    long long n2 = (long long)N * DH / 2;
    h1bf_k<<<(int)((n2 + 255) / 256), 256, 0, stream>>>(h1, h1b, n2);

    // ---- CSR build (per call; deterministic), XCD-partitioned ----
    hipMemsetAsync(cnt, 0, (size_t)N * 4, stream);
    deg2_k<<<8 * NCHUNK, 256, 0, stream>>>(ei, E, cnt, span, chunkE);
    scan1_k<<<B, 256, 0, stream>>>(cnt, N, offs, bsum);
    scan2_k<<<1, 1024, 0, stream>>>(bsum, B);
    scan3_k<<<(N + 255) / 256, 256, 0, stream>>>(offs, cur, dinv, cnt, bsum, N, B);
    fill2_k<<<8 * NCHUNK, 256, 0, stream>>>(ei, E, cur, csr_src, span, chunkE);

    int gblocks = (N + 3) / 4;

    // ---- GCN layer 1 ----
    gemm_mfma_k<<<nstripes, 256, 0, stream>>>(x, w1t, dinv, xq, N);
    gather_k<<<gblocks, 256, 0, stream>>>(csr_src, offs, dinv, (const unsigned short*)xq, g1b, x2b, N);

    // ---- GCN layer 2 (bf16 A) ----
    gemm_mfma_bf_k<<<nstripes, 256, 0, stream>>>((const short*)x2b, w2t, dinv, xq, N);
    gather_k<<<gblocks, 256, 0, stream>>>(csr_src, offs, dinv, (const unsigned short*)xq, g2b, x2b, N);

    // ---- fused GRU chain ----
    gru3_mfma_k<<<nblk64, 512, 0, stream>>>(x2b, h1b, h2, h3,
                                            wb[0], wb[1], wb[2], wb[3], wb[4], wb[5],
                                            bih1, bhh1, bih2, bhh2, bih3, bhh3,
                                            h1n, h2n, h3n, N);
}

// Round 20
// 524.741 us; speedup vs baseline: 1.3085x; 1.0102x over previous
//
#include <hip/hip_runtime.h>
#include <hip/hip_bf16.h>

#define DH 128          // feature dim (D_IN == H == 128)
#define SCB 1024        // scan elements per block
#define NCHUNK 256      // edge chunks for XCD-partitioned CSR build
#define LROW 136        // LDS row stride in shorts (256B + 16B pad)

typedef __attribute__((ext_vector_type(8))) short short8_t;
typedef __attribute__((ext_vector_type(4))) float f32x4;
typedef __attribute__((ext_vector_type(2))) float f32x2;

static __device__ __forceinline__ short f2bf(float f) {
    union { float f; unsigned u; } v; v.f = f;
    unsigned r = v.u + 0x7fffu + ((v.u >> 16) & 1u);   // RNE
    return (short)(r >> 16);
}

static __device__ __forceinline__ float bf2f(unsigned short b) {
    union { unsigned u; float f; } v; v.u = ((unsigned)b) << 16;
    return v.f;
}

static __device__ __forceinline__ short8_t cvt8(const float* p) {
    float4 a0 = *(const float4*)p;
    float4 a1 = *(const float4*)(p + 4);
    short8_t t;
    t[0] = f2bf(a0.x); t[1] = f2bf(a0.y); t[2] = f2bf(a0.z); t[3] = f2bf(a0.w);
    t[4] = f2bf(a1.x); t[5] = f2bf(a1.y); t[6] = f2bf(a1.z); t[7] = f2bf(a1.w);
    return t;
}

static __device__ __forceinline__ short8_t cvt8v(float4 a0, float4 a1) {
    short8_t t;
    t[0] = f2bf(a0.x); t[1] = f2bf(a0.y); t[2] = f2bf(a0.z); t[3] = f2bf(a0.w);
    t[4] = f2bf(a1.x); t[5] = f2bf(a1.y); t[6] = f2bf(a1.z); t[7] = f2bf(a1.w);
    return t;
}

static __device__ __forceinline__ float sigm(float x) {
    return __builtin_amdgcn_rcpf(1.f + __expf(-x));
}
static __device__ __forceinline__ float tanh_f(float x) {
    return 1.f - 2.f * __builtin_amdgcn_rcpf(__expf(2.f * x) + 1.f);
}

// ---------------- degree histogram, XCD-partitioned ----------------
__global__ __launch_bounds__(256) void deg2_k(const int* __restrict__ ei, int E,
                                              unsigned* __restrict__ cnt, int span, int chunkE) {
    int r = blockIdx.x & 7;
    int c = blockIdx.x >> 3;
    int lo = r * span, hi = lo + span;
    long long e0 = (long long)c * chunkE;
    long long e1 = e0 + chunkE; if (e1 > E) e1 = E;
    for (long long e = e0 + threadIdx.x; e < e1; e += 256) {
        int d = ei[E + e];
        if (d >= lo && d < hi) atomicAdd(&cnt[d], 1u);
    }
}

// ---------------- 3-phase grid-parallel exclusive scan ----------------
__global__ __launch_bounds__(256) void scan1_k(const unsigned* __restrict__ cnt, int N,
                                               int* __restrict__ offs, unsigned* __restrict__ bsum) {
    __shared__ unsigned s[256];
    int t = threadIdx.x;
    int i0 = blockIdx.x * SCB + t * 4;
    unsigned v0 = (i0 + 0 < N) ? cnt[i0 + 0] : 0u;
    unsigned v1 = (i0 + 1 < N) ? cnt[i0 + 1] : 0u;
    unsigned v2 = (i0 + 2 < N) ? cnt[i0 + 2] : 0u;
    unsigned v3 = (i0 + 3 < N) ? cnt[i0 + 3] : 0u;
    unsigned ts = v0 + v1 + v2 + v3;
    s[t] = ts;
    __syncthreads();
    for (int off = 1; off < 256; off <<= 1) {
        unsigned u = (t >= off) ? s[t - off] : 0u;
        __syncthreads();
        s[t] += u;
        __syncthreads();
    }
    unsigned ex = s[t] - ts;
    if (i0 + 0 < N) offs[i0 + 0] = (int)ex;
    if (i0 + 1 < N) offs[i0 + 1] = (int)(ex + v0);
    if (i0 + 2 < N) offs[i0 + 2] = (int)(ex + v0 + v1);
    if (i0 + 3 < N) offs[i0 + 3] = (int)(ex + v0 + v1 + v2);
    if (t == 255) bsum[blockIdx.x] = s[255];
}

__global__ __launch_bounds__(1024) void scan2_k(unsigned* __restrict__ bsum, int B) {
    __shared__ unsigned s[1024];
    int t = threadIdx.x;
    unsigned v = (t < B) ? bsum[t] : 0u;
    s[t] = v;
    __syncthreads();
    for (int off = 1; off < 1024; off <<= 1) {
        unsigned u = (t >= off) ? s[t - off] : 0u;
        __syncthreads();
        s[t] += u;
        __syncthreads();
    }
    if (t < B) bsum[t] = s[t] - v;
    if (t == 0) bsum[B] = s[1023];
}

__global__ void scan3_k(int* __restrict__ offs, int* __restrict__ cur,
                        float* __restrict__ dinv, const unsigned* __restrict__ cnt,
                        const unsigned* __restrict__ bsum, int N, int B) {
    int i = blockIdx.x * 256 + threadIdx.x;
    if (i < N) {
        int v = offs[i] + (int)bsum[i >> 10];
        offs[i] = v;
        cur[i] = v;
        dinv[i] = rsqrtf((float)cnt[i] + 1.0f);
    }
    if (i == 0) offs[N] = (int)bsum[B];
}

// ---------------- CSR fill, XCD-partitioned ----------------
__global__ __launch_bounds__(256) void fill2_k(const int* __restrict__ ei, int E,
                                               int* __restrict__ cur, int* __restrict__ csr_src,
                                               int span, int chunkE) {
    int r = blockIdx.x & 7;
    int c = blockIdx.x >> 3;
    int lo = r * span, hi = lo + span;
    long long e0 = (long long)c * chunkE;
    long long e1 = e0 + chunkE; if (e1 > E) e1 = E;
    for (long long e = e0 + threadIdx.x; e < e1; e += 256) {
        int d = ei[E + e];
        if (d >= lo && d < hi) {
            int pos = atomicAdd(&cur[d], 1);
            csr_src[pos] = ei[e];
        }
    }
}

// ---------------- weight prep ----------------
__global__ void f2bf6_k(const float* __restrict__ s0, const float* __restrict__ s1,
                        const float* __restrict__ s2, const float* __restrict__ s3,
                        const float* __restrict__ s4, const float* __restrict__ s5,
                        short* __restrict__ dst, int WN) {
    int i = blockIdx.x * 256 + threadIdx.x;
    if (i >= 6 * WN) return;
    int b = i / WN, r = i - b * WN;
    const float* srcs[6] = {s0, s1, s2, s3, s4, s5};
    dst[i] = f2bf(srcs[b][r]);
}

__global__ void transpose_bf2_k(const float* __restrict__ sa, const float* __restrict__ sb,
                                short* __restrict__ da, short* __restrict__ db) {
    int i = blockIdx.x * 256 + threadIdx.x;   // 2*16384
    int m = i >> 14;
    int j = i & 16383;
    int c = j >> 7, k = j & 127;
    const float* s = m ? sb : sa;
    short* d = m ? db : da;
    d[j] = f2bf(s[k * DH + c]);
}

// h1 fp32 -> packed bf16x2 table
__global__ void h1bf_k(const float* __restrict__ src, unsigned* __restrict__ dst, long long n2) {
    long long i = (long long)blockIdx.x * 256 + threadIdx.x;   // one u32 (2 floats) per thread
    if (i < n2) {
        float2 v = ((const float2*)src)[i];
        dst[i] = (unsigned)(unsigned short)f2bf(v.x) | ((unsigned)(unsigned short)f2bf(v.y) << 16);
    }
}

// ================= MFMA GEMM (fp32 A) -> pre-scaled fp8 table (HW cvt) ===========
__global__ __launch_bounds__(256, 4) void gemm_mfma_k(const float* __restrict__ A,
                                                      const short* __restrict__ Wt,
                                                      const float* __restrict__ dinv,
                                                      unsigned char* __restrict__ C, int N) {
    int tid = threadIdx.x;
    int wave = tid >> 6, lane = tid & 63;
    int lr = lane & 15, kg = lane >> 4;

    int row0 = blockIdx.x * 128 + wave * 32;
    int ar0 = min(row0 + lr, N - 1);
    int ar1 = min(row0 + 16 + lr, N - 1);
    const float* a0p = A + (size_t)ar0 * DH;
    const float* a1p = A + (size_t)ar1 * DH;
    short8_t af[2][4];
#pragma unroll
    for (int ks = 0; ks < 4; ks++) {
        af[0][ks] = cvt8(a0p + ks * 32 + kg * 8);
        af[1][ks] = cvt8(a1p + ks * 32 + kg * 8);
    }

    float di0[4], di1[4];
#pragma unroll
    for (int j = 0; j < 4; j++) {
        di0[j] = dinv[min(row0 + kg * 4 + j, N - 1)];
        di1[j] = dinv[min(row0 + 16 + kg * 4 + j, N - 1)];
    }

    short8_t bt[3][4];
#define GLOADW(slot, t) { \
    const short* wp = Wt + (size_t)((t) * 16 + lr) * DH + kg * 8; \
    bt[slot][0] = *(const short8_t*)(wp); \
    bt[slot][1] = *(const short8_t*)(wp + 32); \
    bt[slot][2] = *(const short8_t*)(wp + 64); \
    bt[slot][3] = *(const short8_t*)(wp + 96); }

    GLOADW(0, 0)
    GLOADW(1, 1)
#pragma unroll
    for (int t = 0; t < 8; t++) {
        if (t < 6) GLOADW((t + 2) % 3, t + 2)
        f32x4 acc0 = {0.f, 0.f, 0.f, 0.f};
        f32x4 acc1 = {0.f, 0.f, 0.f, 0.f};
#pragma unroll
        for (int ks = 0; ks < 4; ks++) {
            acc0 = __builtin_amdgcn_mfma_f32_16x16x32_bf16(af[0][ks], bt[t % 3][ks], acc0, 0, 0, 0);
            acc1 = __builtin_amdgcn_mfma_f32_16x16x32_bf16(af[1][ks], bt[t % 3][ks], acc1, 0, 0, 0);
        }
        int col = t * 16 + lr;
#pragma unroll
        for (int j = 0; j < 4; j++) {
            int g0 = row0 + kg * 4 + j;
            int g1 = row0 + 16 + kg * 4 + j;
            float v0 = acc0[j] * di0[j];
            float v1 = acc1[j] * di1[j];
            if (g0 < N) C[(size_t)g0 * DH + col] =
                (unsigned char)__builtin_amdgcn_cvt_pk_fp8_f32(v0, v0, 0u, false);
            if (g1 < N) C[(size_t)g1 * DH + col] =
                (unsigned char)__builtin_amdgcn_cvt_pk_fp8_f32(v1, v1, 0u, false);
        }
    }
#undef GLOADW
}

// ================= MFMA GEMM (bf16 A) -> pre-scaled fp8 table ===========
__global__ __launch_bounds__(256, 4) void gemm_mfma_bf_k(const short* __restrict__ A, // bf16 rows
                                                         const short* __restrict__ Wt,
                                                         const float* __restrict__ dinv,
                                                         unsigned char* __restrict__ C, int N) {
    int tid = threadIdx.x;
    int wave = tid >> 6, lane = tid & 63;
    int lr = lane & 15, kg = lane >> 4;

    int row0 = blockIdx.x * 128 + wave * 32;
    int ar0 = min(row0 + lr, N - 1);
    int ar1 = min(row0 + 16 + lr, N - 1);
    const short* a0p = A + (size_t)ar0 * DH;
    const short* a1p = A + (size_t)ar1 * DH;
    short8_t af[2][4];
#pragma unroll
    for (int ks = 0; ks < 4; ks++) {
        af[0][ks] = *(const short8_t*)(a0p + ks * 32 + kg * 8);
        af[1][ks] = *(const short8_t*)(a1p + ks * 32 + kg * 8);
    }

    float di0[4], di1[4];
#pragma unroll
    for (int j = 0; j < 4; j++) {
        di0[j] = dinv[min(row0 + kg * 4 + j, N - 1)];
        di1[j] = dinv[min(row0 + 16 + kg * 4 + j, N - 1)];
    }

    short8_t bt[3][4];
#define GLOADW(slot, t) { \
    const short* wp = Wt + (size_t)((t) * 16 + lr) * DH + kg * 8; \
    bt[slot][0] = *(const short8_t*)(wp); \
    bt[slot][1] = *(const short8_t*)(wp + 32); \
    bt[slot][2] = *(const short8_t*)(wp + 64); \
    bt[slot][3] = *(const short8_t*)(wp + 96); }

    GLOADW(0, 0)
    GLOADW(1, 1)
#pragma unroll
    for (int t = 0; t < 8; t++) {
        if (t < 6) GLOADW((t + 2) % 3, t + 2)
        f32x4 acc0 = {0.f, 0.f, 0.f, 0.f};
        f32x4 acc1 = {0.f, 0.f, 0.f, 0.f};
#pragma unroll
        for (int ks = 0; ks < 4; ks++) {
            acc0 = __builtin_amdgcn_mfma_f32_16x16x32_bf16(af[0][ks], bt[t % 3][ks], acc0, 0, 0, 0);
            acc1 = __builtin_amdgcn_mfma_f32_16x16x32_bf16(af[1][ks], bt[t % 3][ks], acc1, 0, 0, 0);
        }
        int col = t * 16 + lr;
#pragma unroll
        for (int j = 0; j < 4; j++) {
            int g0 = row0 + kg * 4 + j;
            int g1 = row0 + 16 + kg * 4 + j;
            float v0 = acc0[j] * di0[j];
            float v1 = acc1[j] * di1[j];
            if (g0 < N) C[(size_t)g0 * DH + col] =
                (unsigned char)__builtin_amdgcn_cvt_pk_fp8_f32(v0, v0, 0u, false);
            if (g1 < N) C[(size_t)g1 * DH + col] =
                (unsigned char)__builtin_amdgcn_cvt_pk_fp8_f32(v1, v1, 0u, false);
        }
    }
#undef GLOADW
}

// ---------------- gather: fp8 table in, packed bf16 out ----------
__global__ __launch_bounds__(256) void gather_k(const int* __restrict__ csr_src,
                                                const int* __restrict__ offs,
                                                const float* __restrict__ dinv,
                                                const unsigned short* __restrict__ xq2, // 2 fp8/ushort
                                                const float* __restrict__ bias,
                                                unsigned* __restrict__ dest, int N) {
    int wid = blockIdx.x * 4 + (threadIdx.x >> 6);
    if (wid >= N) return;
    int lane = threadIdx.x & 63;
    int j = offs[wid];
    int end = offs[wid + 1];
    float dd = dinv[wid];

    f32x2 f0 = __builtin_amdgcn_cvt_pk_f32_fp8((unsigned)xq2[(size_t)wid * 64 + lane], false);
    float ax = f0[0];
    float ay = f0[1];

#define ACC(w) { f32x2 f_ = __builtin_amdgcn_cvt_pk_f32_fp8((unsigned)(w), false); \
                 ax += f_[0]; ay += f_[1]; }

    if (j + 4 <= end) {
        int a0 = csr_src[j], a1 = csr_src[j + 1], a2 = csr_src[j + 2], a3 = csr_src[j + 3];
        j += 4;
        for (; j + 4 <= end; j += 4) {
            unsigned w0 = xq2[(size_t)a0 * 64 + lane];
            unsigned w1 = xq2[(size_t)a1 * 64 + lane];
            unsigned w2 = xq2[(size_t)a2 * 64 + lane];
            unsigned w3 = xq2[(size_t)a3 * 64 + lane];
            a0 = csr_src[j]; a1 = csr_src[j + 1]; a2 = csr_src[j + 2]; a3 = csr_src[j + 3];
            ACC(w0) ACC(w1) ACC(w2) ACC(w3)
        }
        unsigned w0 = xq2[(size_t)a0 * 64 + lane];
        unsigned w1 = xq2[(size_t)a1 * 64 + lane];
        unsigned w2 = xq2[(size_t)a2 * 64 + lane];
        unsigned w3 = xq2[(size_t)a3 * 64 + lane];
        ACC(w0) ACC(w1) ACC(w2) ACC(w3)
    }
    for (; j < end; ++j) {
        unsigned w = xq2[(size_t)csr_src[j] * 64 + lane];
        ACC(w)
    }
#undef ACC

    float2 b2 = ((const float2*)bias)[lane];
    float ox = fmaxf(fmaf(dd, ax, b2.x), 0.f);
    float oy = fmaxf(fmaf(dd, ay, b2.y), 0.f);
    unsigned o = (unsigned)(unsigned short)f2bf(ox) | ((unsigned)(unsigned short)f2bf(oy) << 16);
    dest[(size_t)wid * 64 + lane] = o;
}

// ============ FUSED 3x GRU chain, 4-slot double-buffered LDS, 1 barrier/cell =======
// 512 thr / 8 waves, 64 rows/block. Cell c reads buf b=c&1 (X,H), writes h_next
// and staged H_{c+2} into buf b^1 -> no read/write hazard within a cell, so a
// single end-of-cell barrier suffices (3 barriers/block vs 5).
__global__ __launch_bounds__(512, 1) void gru3_mfma_k(
        const unsigned* __restrict__ Xb,  // bf16x2 rows
        const unsigned* __restrict__ H1b, // bf16x2 rows
        const float* __restrict__ H2, const float* __restrict__ H3,
        const short* __restrict__ w1i, const short* __restrict__ w1h,
        const short* __restrict__ w2i, const short* __restrict__ w2h,
        const short* __restrict__ w3i, const short* __restrict__ w3h,
        const float* __restrict__ bi1, const float* __restrict__ bh1,
        const float* __restrict__ bi2, const float* __restrict__ bh2,
        const float* __restrict__ bi3, const float* __restrict__ bh3,
        float* __restrict__ o1, float* __restrict__ o2, float* __restrict__ o3,
        int N) {
    __shared__ short lds[2][2][64 * LROW];    // ~68 KB: [buf][mat]
    int tid = threadIdx.x;
    int row0 = blockIdx.x * 64;
    int wave = tid >> 6, lane = tid & 63;
    int lr = lane & 15, kg = lane >> 4;
    int c0 = wave * 16;

    const short* wihs[3] = {w1i, w2i, w3i};
    const short* whhs[3] = {w1h, w2h, w3h};
    const float* bihs[3] = {bi1, bi2, bi3};
    const float* bhhs[3] = {bh1, bh2, bh3};
    float* outs[3] = {o1, o2, o3};

    short8_t bw[3][4], bu[3][4];   // weight frags for CURRENT cell
#define WLOADALL(wih_, whh_) { \
    _Pragma("unroll") \
    for (int g = 0; g < 3; g++) { \
        const short* wi = (wih_) + (size_t)(g * DH + c0 + lr) * DH + kg * 8; \
        const short* wh = (whh_) + (size_t)(g * DH + c0 + lr) * DH + kg * 8; \
        _Pragma("unroll") \
        for (int ks = 0; ks < 4; ks++) { \
            bw[g][ks] = *(const short8_t*)(wi + ks * 32); \
            bu[g][ks] = *(const short8_t*)(wh + ks * 32); \
        } \
    } }

    WLOADALL(w1i, w1h)

    // ---- initial stage: X,H1 packed-bf16 pure copy into buf 0 ----
    {
        int mat = tid >> 8;            // 0=X, 1=H1
        int r = (tid & 255) >> 2;      // 0..63
        int q = tid & 3;               // 32-col (16 u32) chunk
        int grow = min(row0 + r, N - 1);
        const uint4* src4 = (const uint4*)((mat ? H1b : Xb) + (size_t)grow * 64 + q * 16);
        uint4 a = src4[0], b = src4[1], c = src4[2], d = src4[3];
        char* dst = (char*)&lds[0][mat][r * LROW] + q * 64;
        *(uint4*)(dst + 0)  = a;
        *(uint4*)(dst + 16) = b;
        *(uint4*)(dst + 32) = c;
        *(uint4*)(dst + 48) = d;
    }
    __syncthreads();

    int gcol = c0 + lr;
    int colb = gcol * 2;               // byte offset of this lane's column
    int srow = tid >> 3;               // staging row (0..63)
    int sq = tid & 7;                  // staging 16-col chunk

#pragma unroll
    for (int cell = 0; cell < 3; cell++) {
        int b = cell & 1;              // read buffer (0,1,0)
        const short* ldsX = lds[b][0];
        const short* ldsH = lds[b][1];
        short* nxtX = lds[b ^ 1][0];
        short* nxtH = lds[b ^ 1][1];

        // ---- MFMA phase ----
        f32x4 aR[4], aZ[4], aI[4], aH[4];
#pragma unroll
        for (int rt = 0; rt < 4; rt++) {
            aR[rt] = (f32x4){0,0,0,0}; aZ[rt] = (f32x4){0,0,0,0};
            aI[rt] = (f32x4){0,0,0,0}; aH[rt] = (f32x4){0,0,0,0};
        }
#pragma unroll
        for (int rt = 0; rt < 4; rt++) {
            int r = rt * 16 + lr;
            const char* xrow = (const char*)&ldsX[r * LROW];
            const char* hrow = (const char*)&ldsH[r * LROW];
            short8_t xa[4], ha[4];
#pragma unroll
            for (int ks = 0; ks < 4; ks++) {
                int boff = ks * 64 + kg * 16;
                xa[ks] = *(const short8_t*)(xrow + boff);
                ha[ks] = *(const short8_t*)(hrow + boff);
            }
#pragma unroll
            for (int ks = 0; ks < 4; ks++) {
                aR[rt] = __builtin_amdgcn_mfma_f32_16x16x32_bf16(xa[ks], bw[0][ks], aR[rt], 0, 0, 0);
                aR[rt] = __builtin_amdgcn_mfma_f32_16x16x32_bf16(ha[ks], bu[0][ks], aR[rt], 0, 0, 0);
                aZ[rt] = __builtin_amdgcn_mfma_f32_16x16x32_bf16(xa[ks], bw[1][ks], aZ[rt], 0, 0, 0);
                aZ[rt] = __builtin_amdgcn_mfma_f32_16x16x32_bf16(ha[ks], bu[1][ks], aZ[rt], 0, 0, 0);
                aI[rt] = __builtin_amdgcn_mfma_f32_16x16x32_bf16(xa[ks], bw[2][ks], aI[rt], 0, 0, 0);
                aH[rt] = __builtin_amdgcn_mfma_f32_16x16x32_bf16(ha[ks], bu[2][ks], aH[rt], 0, 0, 0);
            }
        }

        // ---- T14: issue next-H global loads NOW; epilogue covers the latency ----
        float4 hs0, hs1, hs2, hs3;
        if (cell < 2) {
            int grow = min(row0 + srow, N - 1);
            const float* src = (cell == 0 ? H2 : H3) + (size_t)grow * DH + sq * 16;
            hs0 = *(const float4*)(src + 0);
            hs1 = *(const float4*)(src + 4);
            hs2 = *(const float4*)(src + 8);
            hs3 = *(const float4*)(src + 12);
        }

        // ---- epilogue (hv from read buffer) ----
        const float* bih = bihs[cell];
        const float* bhh = bhhs[cell];
        float br = bih[gcol], bz = bih[DH + gcol], bn = bih[2 * DH + gcol];
        float cr = bhh[gcol], cz = bhh[DH + gcol], cn = bhh[2 * DH + gcol];
        float* outp = outs[cell];
        short hb[4][4];                 // bf16 h_next
#pragma unroll
        for (int rt = 0; rt < 4; rt++) {
#pragma unroll
            for (int j = 0; j < 4; j++) {
                int r = rt * 16 + kg * 4 + j;
                float hv = bf2f(*(const unsigned short*)((const char*)&ldsH[r * LROW] + colb));
                float rr = sigm(aR[rt][j] + br + cr);
                float zz = sigm(aZ[rt][j] + bz + cz);
                float nn = tanh_f(aI[rt][j] + bn + rr * (aH[rt][j] + cn));
                float ov = fmaf(zz, hv - nn, nn);
                int grow = row0 + r;
                if (grow < N) outp[(size_t)grow * DH + gcol] = ov;
                hb[rt][j] = f2bf(ov);
            }
        }

        if (cell < 2) {
            // ---- prefetch next cell's weights ----
            WLOADALL(wihs[cell + 1], whhs[cell + 1])

            // write h_next (bf16) into NEXT buffer's X slot (no hazard: nobody
            // reads buf^1 this cell)
#pragma unroll
            for (int rt = 0; rt < 4; rt++) {
#pragma unroll
                for (int j = 0; j < 4; j++) {
                    int r = rt * 16 + kg * 4 + j;
                    *(short*)((char*)&nxtX[r * LROW] + colb) = hb[rt][j];
                }
            }
            // staged H_{cell+2} -> NEXT buffer's H slot
            {
                char* dst = (char*)&nxtH[srow * LROW] + sq * 32;
                *(short8_t*)(dst) = cvt8v(hs0, hs1);
                *(short8_t*)(dst + 16) = cvt8v(hs2, hs3);
            }
            __syncthreads();   // single barrier: next-buffer writes visible
        }
    }
#undef WLOADALL
}

extern "C" void kernel_launch(void* const* d_in, const int* in_sizes, int n_in,
                              void* d_out, int out_size, void* d_ws, size_t ws_size,
                              hipStream_t stream) {
    const float* x    = (const float*)d_in[0];
    const int*   ei   = (const int*)d_in[1];
    const float* h1   = (const float*)d_in[2];
    const float* h2   = (const float*)d_in[3];
    const float* h3   = (const float*)d_in[4];
    const float* g1w  = (const float*)d_in[5];
    const float* g1b  = (const float*)d_in[6];
    const float* g2w  = (const float*)d_in[7];
    const float* g2b  = (const float*)d_in[8];
    const float* wih1 = (const float*)d_in[9];
    const float* whh1 = (const float*)d_in[10];
    const float* bih1 = (const float*)d_in[11];
    const float* bhh1 = (const float*)d_in[12];
    const float* wih2 = (const float*)d_in[13];
    const float* whh2 = (const float*)d_in[14];
    const float* bih2 = (const float*)d_in[15];
    const float* bhh2 = (const float*)d_in[16];
    const float* wih3 = (const float*)d_in[17];
    const float* whh3 = (const float*)d_in[18];
    const float* bih3 = (const float*)d_in[19];
    const float* bhh3 = (const float*)d_in[20];

    int N = in_sizes[0] / DH;
    int E = in_sizes[1] / 2;
    int B = (N + SCB - 1) / SCB;
    int nstripes = (N + 127) / 128;
    int nblk64 = (N + 63) / 64;
    int span = (N + 7) / 8;
    int chunkE = (E + NCHUNK - 1) / NCHUNK;

    char* wsp = (char*)d_ws;
    auto alloc = [&](size_t bytes) -> char* {
        char* p = wsp;
        wsp += (bytes + 63) & ~(size_t)63;
        return p;
    };
    unsigned* cnt = (unsigned*)alloc((size_t)N * 4);
    int* offs     = (int*)alloc(((size_t)N + 1) * 4);
    int* cur      = (int*)alloc((size_t)N * 4);
    float* dinv   = (float*)alloc((size_t)N * 4);
    unsigned* bsum= (unsigned*)alloc(((size_t)B + 1) * 4);
    int* csr_src  = (int*)alloc((size_t)E * 4);
    unsigned char* xq = (unsigned char*)alloc((size_t)N * DH);   // fp8 pre-scaled table
    unsigned* x2b = (unsigned*)alloc((size_t)N * DH * 2);        // bf16x2 activations
    unsigned* h1b = (unsigned*)alloc((size_t)N * DH * 2);        // bf16x2 h1
    short* w1t    = (short*)alloc((size_t)DH * DH * 2);
    short* w2t    = (short*)alloc((size_t)DH * DH * 2);
    const int WN = 3 * DH * DH;      // 49152
    short* wbAll  = (short*)alloc((size_t)6 * WN * 2);
    short* wb[6];
    for (int i = 0; i < 6; i++) wb[i] = wbAll + (size_t)i * WN;

    float* out  = (float*)d_out;
    float* h1n  = out;
    float* h2n  = out + (size_t)N * DH;
    float* h3n  = out + 2 * (size_t)N * DH;

    // ---- weight/activation prep (bf16) ----
    f2bf6_k<<<(6 * WN + 255) / 256, 256, 0, stream>>>(wih1, whh1, wih2, whh2, wih3, whh3, wbAll, WN);
    transpose_bf2_k<<<(2 * DH * DH + 255) / 256, 256, 0, stream>>>(g1w, g2w, w1t, w2t);
    long long n2 = (long long)N * DH / 2;
    h1bf_k<<<(int)((n2 + 255) / 256), 256, 0, stream>>>(h1, h1b, n2);

    // ---- CSR build (per call; deterministic), XCD-partitioned ----
    hipMemsetAsync(cnt, 0, (size_t)N * 4, stream);
    deg2_k<<<8 * NCHUNK, 256, 0, stream>>>(ei, E, cnt, span, chunkE);
    scan1_k<<<B, 256, 0, stream>>>(cnt, N, offs, bsum);
    scan2_k<<<1, 1024, 0, stream>>>(bsum, B);
    scan3_k<<<(N + 255) / 256, 256, 0, stream>>>(offs, cur, dinv, cnt, bsum, N, B);
    fill2_k<<<8 * NCHUNK, 256, 0, stream>>>(ei, E, cur, csr_src, span, chunkE);

    int gblocks = (N + 3) / 4;

    // ---- GCN layer 1 ----
    gemm_mfma_k<<<nstripes, 256, 0, stream>>>(x, w1t, dinv, xq, N);
    gather_k<<<gblocks, 256, 0, stream>>>(csr_src, offs, dinv, (const unsigned short*)xq, g1b, x2b, N);

    // ---- GCN layer 2 (bf16 A) ----
    gemm_mfma_bf_k<<<nstripes, 256, 0, stream>>>((const short*)x2b, w2t, dinv, xq, N);
    gather_k<<<gblocks, 256, 0, stream>>>(csr_src, offs, dinv, (const unsigned short*)xq, g2b, x2b, N);

    // ---- fused GRU chain ----
    gru3_mfma_k<<<nblk64, 512, 0, stream>>>(x2b, h1b, h2, h3,
                                            wb[0], wb[1], wb[2], wb[3], wb[4], wb[5],
                                            bih1, bhh1, bih2, bhh2, bih3, bhh3,
                                            h1n, h2n, h3n, N);
}